// Round 10
// baseline (463.350 us; speedup 1.0000x reference)
//
#include <hip/hip_runtime.h>
#include <hip/hip_bf16.h>

typedef __attribute__((ext_vector_type(8))) short short8;
typedef __attribute__((ext_vector_type(4))) short short4v;
typedef __attribute__((ext_vector_type(4))) float floatx4;

#define EDIM 256
#define HDIM 512
#define LDIM 16
#define NCOL 2048
#define BM 256      // chains per block
#define KC 32       // k-chunk

__device__ __forceinline__ float fsigmoid(float x){ return 1.0f/(1.0f+__expf(-x)); }
__device__ __forceinline__ float ftanh(float x){ return 2.0f/(1.0f+__expf(-2.0f*x))-1.0f; }
__device__ __forceinline__ float bf2f(short s){
    union { unsigned u; float f; } cv; cv.u = ((unsigned)(unsigned short)s) << 16; return cv.f;
}
__device__ __forceinline__ unsigned short f2bf_bits(float v){
    union { __hip_bfloat16 h; unsigned short u; } cv;
    cv.h = __float2bfloat16(v); return cv.u;
}

// ---- coherent (L2-bypassing, write-through) primitives; compiler-managed.
__device__ __forceinline__ short8 aload16(const short* p) {
    union { unsigned long long q[2]; short8 s; } u;
    u.q[0] = __hip_atomic_load((const unsigned long long*)p,
                               __ATOMIC_RELAXED, __HIP_MEMORY_SCOPE_AGENT);
    u.q[1] = __hip_atomic_load((const unsigned long long*)p + 1,
                               __ATOMIC_RELAXED, __HIP_MEMORY_SCOPE_AGENT);
    return u.s;
}
__device__ __forceinline__ void astore_bf16(short* p, float v) {
    __hip_atomic_store((unsigned short*)p, f2bf_bits(v),
                       __ATOMIC_RELAXED, __HIP_MEMORY_SCOPE_AGENT);
}
__device__ __forceinline__ unsigned ald(const unsigned* p) {
    return __hip_atomic_load(p, __ATOMIC_RELAXED, __HIP_MEMORY_SCOPE_AGENT);
}
__device__ __forceinline__ void ast(unsigned* p, unsigned v) {
    __hip_atomic_store(p, v, __ATOMIC_RELAXED, __HIP_MEMORY_SCOPE_AGENT);
}
// poll 4 consecutive flag words until all >= v (one pipelined load burst/iter)
__device__ __forceinline__ void waitflags4(const unsigned* f, unsigned v) {
    for (;;) {
        unsigned a = ald(f + 0), b = ald(f + 1);
        unsigned c = ald(f + 2), d = ald(f + 3);
        if (a >= v && b >= v && c >= v && d >= v) break;
        __builtin_amdgcn_s_sleep(1);
    }
}
// LDS-only barrier: waves sync WITHOUT draining vmcnt (T4): staging loads
// stay in flight across chunk boundaries.
__device__ __forceinline__ void lds_barrier() {
    asm volatile("s_waitcnt lgkmcnt(0)" ::: "memory");
    __builtin_amdgcn_s_barrier();
}

__device__ __forceinline__ bool detect_bf16(const short* p) {
    // fp32 buffers' even shorts are low mantissa bits (~uniform) -> exponent
    // field frequently > 0x7B; true bf16 U(-.05,.05) weights never exceed it.
    bool bf = true;
    for (int i = 0; i < 64; i += 2) {
        int e = (((unsigned short)p[i]) >> 7) & 0xFF;
        if (e > 0x7B) bf = false;
    }
    return bf;
}

// ---------------------------------------------------------------------------
// W_hh -> bf16 (copy if already bf16). Zeroes the 9216-word sync area:
// wdone[mt][jt] @ mt*16+jt (contiguous per-mt line for 4-wide polls);
// kdone[mt][jt] @ 1024 + (mt*16+jt)*32 (padded: 16 parallel pollers).
// ---------------------------------------------------------------------------
__global__ void conv_whh(const void* __restrict__ whhp, short* __restrict__ whh_o,
                         unsigned* __restrict__ sync) {
    if (blockIdx.x == 0)
        for (int i = threadIdx.x; i < 9216; i += 256) sync[i] = 0u;
    bool bf = detect_bf16((const short*)whhp);
    int tid = blockIdx.x * blockDim.x + threadIdx.x;
    int stride = gridDim.x * blockDim.x;
    if (bf) {
        const short* s = (const short*)whhp;
        for (int i = tid; i < NCOL * HDIM; i += stride) whh_o[i] = s[i];
    } else {
        const float* s = (const float*)whhp;
        for (int i = tid; i < NCOL * HDIM; i += stride)
            ((__hip_bfloat16*)whh_o)[i] = __float2bfloat16(s[i]);
    }
}

// ---------------------------------------------------------------------------
// xg[id][j][g] = emb[id] . W_ih[g*512+j] + b_ih + b_hh   (bf16 out)
// Layout is [id][j][4 gates] so the LSTM epilogue gathers one 8B vector.
// ---------------------------------------------------------------------------
__global__ void build_xg(const void* __restrict__ embp, const void* __restrict__ wihp,
                         const void* __restrict__ bihp, const void* __restrict__ bhhp,
                         short* __restrict__ xg)
{
    __shared__ float es[16][EDIM];        // 16 KB
    __shared__ float wsm[32][EDIM + 1];   // 32.1 KB (pad breaks bank conflicts)
    bool bf = detect_bf16((const short*)wihp);
    const int idt = blockIdx.x, ct = blockIdx.y, tt = threadIdx.x;

    if (bf) {
        const __hip_bfloat16* e = (const __hip_bfloat16*)embp;
        const __hip_bfloat16* wv = (const __hip_bfloat16*)wihp;
        for (int p = 0; p < 16; ++p) es[p][tt] = __bfloat162float(e[(idt*16+p)*EDIM + tt]);
        for (int p = 0; p < 32; ++p) wsm[p][tt] = __bfloat162float(wv[(ct*32+p)*EDIM + tt]);
    } else {
        const float* e = (const float*)embp;
        const float* wv = (const float*)wihp;
        for (int p = 0; p < 16; ++p) es[p][tt] = e[(idt*16+p)*EDIM + tt];
        for (int p = 0; p < 32; ++p) wsm[p][tt] = wv[(ct*32+p)*EDIM + tt];
    }
    __syncthreads();

    const int col_l = tt & 31, grp = tt >> 5;   // 8 groups x 2 ids
    const int col = ct * 32 + col_l;            // 0..2047, gate-major
    float bsum = bf ? (__bfloat162float(((const __hip_bfloat16*)bihp)[col]) +
                       __bfloat162float(((const __hip_bfloat16*)bhhp)[col]))
                    : (((const float*)bihp)[col] + ((const float*)bhhp)[col]);
    float a0 = 0.f, a1 = 0.f;
    for (int k = 0; k < EDIM; ++k) {
        float wv = wsm[col_l][k];
        a0 += es[grp*2+0][k] * wv;
        a1 += es[grp*2+1][k] * wv;
    }
    const int jj = col & (HDIM - 1), gsel = col >> 9;
    ((__hip_bfloat16*)xg)[(idt*16 + grp*2 + 0)*NCOL + jj*4 + gsel] = __float2bfloat16(a0 + bsum);
    ((__hip_bfloat16*)xg)[(idt*16 + grp*2 + 1)*NCOL + jj*4 + gsel] = __float2bfloat16(a1 + bsum);
}

// ---------------------------------------------------------------------------
// Fully fused LSTM with CHUNK-GRANULAR producer/consumer sync (this round):
// the per-step 16-block rendezvous (skew sums over the group) is replaced by
//  - forward flags: wdone[mt][kc] >= t gates staging of K-chunk kc (chunk kc
//    of h is produced exactly by block (mt,kc)); polled 4-wide, 2+ chunks
//    ahead of use -> block skew pipelines instead of summing.
//  - backward flags: kdone[mt][jt] = t after a block's k-loop (all its h
//    reads complete); producer gates h-writes (ping-pong WAR) on all 16
//    kdone >= t-1 via 16 parallel pollers.
// Dependencies flow strictly to earlier steps -> acyclic -> deadlock-free.
// Visibility: round-9-proven relaxed agent atomics (write-through h, L2-
// bypass loads), syncthreads-drain-then-flag. Zero cache maintenance.
// Everything else (W_hh in LDS, T4 chunk barriers, distance-2 staging,
// register c/h state, xv prefetch) carried from round 9.
// ---------------------------------------------------------------------------
__launch_bounds__(512, 2)
__global__ void lstm_fused(const int* __restrict__ seq, const int* __restrict__ lens,
                           const short* __restrict__ whh,   // bf16 [2048][512]
                           const short* __restrict__ xg,    // bf16 [256][512][4]
                           short* __restrict__ hb0, short* __restrict__ hb1,
                           float* __restrict__ out,         // fp32 [4096][512]
                           unsigned* __restrict__ sync)
{
    __shared__ __align__(16) short Bs[128 * 512];   // 128 KB, swizzled
    __shared__ __align__(16) short As[2][BM * KC];  // 32 KB, swizzled

    const int f  = blockIdx.x;
    // XCD swizzle: all 16 jt-blocks of an mt tend to land on one XCD (perf
    // only; correctness is placement-independent).
    const int mt = ((f & 7) << 1) | ((f >> 3) & 1);
    const int jt = f >> 4;
    const int tid = threadIdx.x;
    const int wave = tid >> 6, lane = tid & 63;
    const int q = lane >> 4, ln = lane & 15;
    const int ms = wave & 3, ns = wave >> 2;
    const int jloc = ns * 16 + ln;        // 0..31 within block's j-slab
    const int jglob = jt * 32 + jloc;

    unsigned* const wd = sync + mt * 16;                 // wdone[jt], contiguous
    unsigned* const kd = sync + 1024 + (mt * 16) * 32;   // kdone[jt], stride 32

    // ---- stage W_hh slab into LDS once: rows g*32+jl <- whh[g*512+jt*32+jl]
    // swizzle: elem col c stored at c ^ ((row&7)<<3)  (16B-group XOR)
#pragma unroll
    for (int it = 0; it < 16; ++it) {
        int task = it * 512 + tid;            // 8192 tasks of 16 B
        int row = task >> 6, seg = task & 63;
        int grow = (row >> 5) * HDIM + jt * 32 + (row & 31);
        short8 v = *(const short8*)(whh + grow * HDIM + seg * 8);
        *(short8*)&Bs[row * 512 + ((seg * 8) ^ ((row & 7) << 3))] = v;
    }

    const int chainbase = mt * BM + ms * 64 + q * 4;
    const int obase = chainbase * HDIM + jglob;

    // staging task constants: thread covers rows srow and 128+srow, 16 B each
    const int srow = tid >> 2, sseg = tid & 3;
    const int g0 = srow * HDIM + sseg * 8;           // global elem offsets
    const int g1 = (128 + srow) * HDIM + sseg * 8;
    const int l0 = srow * KC + ((sseg * 8) ^ ((srow & 3) << 3));        // LDS
    const int l1 = (128 + srow) * KC + ((sseg * 8) ^ ((srow & 3) << 3));

    // packed lens (values 1..16 fit a byte) -> 4 VGPRs
    unsigned lnspk[4] = {0u, 0u, 0u, 0u};
#pragma unroll
    for (int e = 0; e < 16; ++e)
        lnspk[e >> 2] |= ((unsigned)lens[chainbase + (e >> 2) * 16 + (e & 3)] & 0xFFu)
                         << ((e & 3) * 8);

    float c_st[16], h_st[16];
#pragma unroll
    for (int e = 0; e < 16; ++e) { c_st[e] = 0.f; h_st[e] = 0.f; }

    // prefetch t=0 ids + gate vectors (normal cached loads: read-only data)
    int idsN[16];
    short4v xv[16];
#pragma unroll
    for (int e = 0; e < 16; ++e)
        idsN[e] = seq[(chainbase + (e >> 2) * 16 + (e & 3)) * LDIM + 0];
#pragma unroll
    for (int e = 0; e < 16; ++e)
        xv[e] = *(const short4v*)(xg + idsN[e] * NCOL + jglob * 4);

    for (int t = 0; t < LDIM; ++t) {
        const short* hr = (t & 1) ? hb1 : hb0;   // written at step t-1
        short* hw       = (t & 1) ? hb0 : hb1;
        const bool notlast = (t < LDIM - 1);

        // seq ids for t+1: read-only, issue now, land during the GEMM
        if (notlast) {
#pragma unroll
            for (int e = 0; e < 16; ++e)
                idsN[e] = seq[(chainbase + (e >> 2) * 16 + (e & 3)) * LDIM + t + 1];
        }

        floatx4 acc[4][4];  // [gate][mfrag]
#pragma unroll
        for (int g = 0; g < 4; ++g)
#pragma unroll
            for (int mf = 0; mf < 4; ++mf) acc[g][mf] = (floatx4){0.f, 0.f, 0.f, 0.f};

        if (t > 0) {
            const unsigned si = (unsigned)t;
            const short* abase = hr + (size_t)mt * BM * HDIM;
            // forward gate for chunks 0..3 (producers 0..3 finished t-1)
            waitflags4(wd + 0, si);
            // rq[parity][p]: distance-2 register staging pipeline
            short8 rq[2][2];
            {   // prologue: chunk 0 -> LDS; chunk 1 -> regs
                short8 v0 = aload16(abase + g0);
                short8 v1 = aload16(abase + g1);
                rq[1][0]  = aload16(abase + g0 + KC);
                rq[1][1]  = aload16(abase + g1 + KC);
                *(short8*)&As[0][l0] = v0;
                *(short8*)&As[0][l1] = v1;
            }
            lds_barrier();
#pragma unroll
            for (int kc = 0; kc < 16; ++kc) {
                const int b = kc & 1;
                // ds_write chunk kc+1 (regs, loaded 2 chunks ago)
                if (kc < 15) {
                    *(short8*)&As[b ^ 1][l0] = rq[(kc + 1) & 1][0];
                    *(short8*)&As[b ^ 1][l1] = rq[(kc + 1) & 1][1];
                }
                // forward gates, 4 chunks at a time, >=2 chunks ahead of use
                if (kc == 0) waitflags4(wd + 4,  si);
                if (kc == 4) waitflags4(wd + 8,  si);
                if (kc == 8) waitflags4(wd + 12, si);
                // issue global load for chunk kc+2 (stays in flight across
                // the vmcnt-free chunk barriers)
                if (kc < 14) {
                    rq[kc & 1][0] = aload16(abase + g0 + (kc + 2) * KC);
                    rq[kc & 1][1] = aload16(abase + g1 + (kc + 2) * KC);
                }
                // compute on buffer b
                short8 af[4], bfr[4];
#pragma unroll
                for (int mf = 0; mf < 4; ++mf)
                    af[mf] = *(const short8*)&As[b][(ms * 64 + mf * 16 + ln) * KC +
                                                    ((q * 8) ^ ((ln & 3) << 3))];
#pragma unroll
                for (int g = 0; g < 4; ++g)
                    bfr[g] = *(const short8*)&Bs[(g * 32 + jloc) * 512 +
                                                 ((kc * 32 + q * 8) ^ ((ln & 7) << 3))];
                __builtin_amdgcn_s_setprio(1);
#pragma unroll
                for (int g = 0; g < 4; ++g)
#pragma unroll
                    for (int mf = 0; mf < 4; ++mf)
                        acc[g][mf] = __builtin_amdgcn_mfma_f32_16x16x32_bf16(
                            af[mf], bfr[g], acc[g][mf], 0, 0, 0);
                __builtin_amdgcn_s_setprio(0);
                lds_barrier();   // LDS-only: global loads NOT drained (T4)
            }
            // all hr reads physically complete (drained by ds_writes + final
            // barrier) -> publish k-loop completion for WAR gating
            if (tid == 0) ast(kd + jt * 32, si);
        }

        // ---- backward WAR gate: before overwriting the buffer read at step
        // t-1, wait until all 16 blocks finished their step t-1 k-loop.
        if (t >= 2 && t < 15) {
            if (tid < 16) {
                const unsigned need = (unsigned)(t - 1);
                while (ald(kd + tid * 32) < need)
                    __builtin_amdgcn_s_sleep(1);
            }
            __syncthreads();
        }

        // ---- epilogue: prefetched xg + cell update. C/D: col=ln, row=q*4+r
#pragma unroll
        for (int e = 0; e < 16; ++e) {
            const int mf = e >> 2, r = e & 3;
            float p0 = acc[0][mf][r] + bf2f(xv[e][0]);
            float p1 = acc[1][mf][r] + bf2f(xv[e][1]);
            float p2 = acc[2][mf][r] + bf2f(xv[e][2]);
            float p3 = acc[3][mf][r] + bf2f(xv[e][3]);
            float ig = fsigmoid(p0);
            float fg = fsigmoid(p1);
            float gg = ftanh(p2);
            float og = fsigmoid(p3);
            float cn = fg * c_st[e] + ig * gg;
            float hn = og * ftanh(cn);
            bool mk = (int)((lnspk[e >> 2] >> ((e & 3) * 8)) & 0xFFu) > t;
            float hsv = mk ? hn : h_st[e];
            float csv = mk ? cn : c_st[e];
            h_st[e] = hsv; c_st[e] = csv;
            int off = obase + (mf * 16 + r) * HDIM;
            if (notlast) astore_bf16(hw + off, hsv);   // coherent write-through
            else         out[off] = hsv;               // final h, fp32
        }

        // ---- publish this step's h: drain all waves' stores (syncthreads
        // = vmcnt(0) per wave + barrier), then set forward flag. Consumers
        // of chunk jt poll wd[jt]. xv prefetch overlaps next-step prologue.
        if (notlast) {
            __syncthreads();
            if (tid == 0) ast(wd + jt, (unsigned)(t + 1));
#pragma unroll
            for (int e = 0; e < 16; ++e)     // xg for t+1 (read-only, cached)
                xv[e] = *(const short4v*)(xg + idsN[e] * NCOL + jglob * 4);
        }
    }
}

extern "C" void kernel_launch(void* const* d_in, const int* in_sizes, int n_in,
                              void* d_out, int out_size, void* d_ws, size_t ws_size,
                              hipStream_t stream) {
    const int* seq  = (const int*)d_in[0];
    const int* lens = (const int*)d_in[1];

    // ws: h_even 4M | h_odd 4M | xg 1M | whh_bf 2M | sync 36KB (< 11.14M cap)
    char* w = (char*)d_ws;
    short* h_even = (short*)w;
    short* h_odd  = (short*)(w + 4u*1024*1024);
    short* xg     = (short*)(w + 8u*1024*1024);
    short* whh_bf = (short*)(w + 9u*1024*1024);
    unsigned* syn = (unsigned*)(w + 11u*1024*1024);
    float* outp   = (float*)d_out;

    conv_whh<<<512, 256, 0, stream>>>(d_in[4], whh_bf, syn);
    build_xg<<<dim3(16, 64), 256, 0, stream>>>(d_in[2], d_in[3], d_in[5], d_in[6], xg);
    lstm_fused<<<256, 512, 0, stream>>>(seq, lens, whh_bf, xg, h_even, h_odd, outp, syn);
}